// Round 2
// baseline (184.732 us; speedup 1.0000x reference)
//
#include <hip/hip_runtime.h>
#include <math.h>

// Problem constants (fixed by reference)
#define H_DIM 256
#define NHEAD 8
#define DHEAD 32
#define NB 2
#define TSEQ 2048
#define LN_EPS 1e-5f

// softmax in exp2 domain: logit2 = s * (100/sqrt(32)) * log2(e).
// QK2_SCALE is folded into the packed Q fragments (proj frag-gen).
#define QK2_SCALE 25.503486f
#define SPLIT 2                         // key-split factor
#define TILES_PER (TSEQ / 64 / SPLIT)   // 16 k-tiles per block

typedef _Float16 half8 __attribute__((ext_vector_type(8)));
typedef _Float16 half4t __attribute__((ext_vector_type(4)));
typedef _Float16 half2t __attribute__((ext_vector_type(2)));
typedef float f32x4 __attribute__((ext_vector_type(4)));

__device__ __forceinline__ f32x4 mfma16(half8 a, half8 b, f32x4 c) {
  return __builtin_amdgcn_mfma_f32_16x16x32_f16(a, b, c, 0, 0, 0);
}
__device__ __forceinline__ float exp2fast(float x) {
  return __builtin_amdgcn_exp2f(x);
}
__device__ __forceinline__ half2t pkrtz(float a, float b) {
  return __builtin_bit_cast(half2t, __builtin_amdgcn_cvt_pkrtz(a, b));
}

// ---------------- fused masks + W pre-pack (+ combine-counter zero) --------
// blocks < 2048: qmask/kmask = sign(sum|x|) per row of Q/K.
// blocks >= 2048: W fp32 -> hi/lo f16 B-fragment layout (no mask dependency).
__global__ __launch_bounds__(256) void setup_kernel(
    const float* __restrict__ Q, const float* __restrict__ K,
    const float* __restrict__ Wq, const float* __restrict__ Wk, const float* __restrict__ Wv,
    float* __restrict__ qmask, float* __restrict__ kmask,
    half8* __restrict__ WpkHi, half8* __restrict__ WpkLo, int* __restrict__ ctr) {
  const int tid = threadIdx.x;
  if (blockIdx.x < 2048) {
    if (blockIdx.x == 0 && tid < 64) ctr[tid] = 0;   // split-k combine counters
    const int wid = tid >> 6, lane = tid & 63;
    int row = blockIdx.x * 4 + wid;
    const int total_q = NB * TSEQ;
    const float* src;
    float* dst;
    if (row < total_q) { src = Q + (size_t)row * H_DIM; dst = qmask + row; }
    else               { src = K + (size_t)(row - total_q) * H_DIM; dst = kmask + (row - total_q); }
    float4 v = *(const float4*)(src + lane * 4);
    float s = fabsf(v.x) + fabsf(v.y) + fabsf(v.z) + fabsf(v.w);
    #pragma unroll
    for (int off = 32; off > 0; off >>= 1) s += __shfl_xor(s, off);
    if (lane == 0) *dst = (s != 0.0f) ? 1.0f : 0.0f;
    return;
  }
  int slot = (blockIdx.x - 2048) * 256 + tid;   // 0..24575
  int lane = slot & 63;
  int fg = (slot >> 6) & 15;
  int s  = (slot >> 10) & 7;
  int which = slot >> 13;
  const float* W = which == 0 ? Wq : which == 1 ? Wk : Wv;
  int j  = fg * 16 + (lane & 15);
  int kb = s * 32 + (lane >> 4) * 8;
  half8 hi, lo;
  #pragma unroll
  for (int jj = 0; jj < 8; ++jj) {
    float x = W[(size_t)(kb + jj) * H_DIM + j];
    _Float16 h = (_Float16)x;
    hi[jj] = h;
    lo[jj] = (_Float16)(x - (float)h);
  }
  WpkHi[slot] = hi;
  WpkLo[slot] = lo;
}

// ---------------- fused projection + frag repack (+ AmaskF emit) ----------------
// relu(X@W+b) via split-fp16 MFMA; result tile (64 t x 64 j = 2 heads) goes
// through LDS transpose and exits directly as MFMA fragment arrays:
//   Q/K: hi/lo split-f16 frags (Q pre-scaled by QK2_SCALE)
//   V:   transposed f16 frags, kmask- and t==2047-zeroed.
// which==1, x==0 blocks additionally emit AmaskF (mask-row A-fragments).
__global__ __launch_bounds__(256) void proj_kernel(
    const float* __restrict__ Q, const float* __restrict__ K, const float* __restrict__ V,
    const float* __restrict__ bq, const float* __restrict__ bk, const float* __restrict__ bv,
    const half8* __restrict__ WpkHi, const half8* __restrict__ WpkLo,
    const float* __restrict__ kmask,
    half8* __restrict__ Gqhi, half8* __restrict__ Gqlo,
    half8* __restrict__ Gkhi, half8* __restrict__ Gklo, half8* __restrict__ Gv,
    half8* __restrict__ AmaskF) {
  const int which = blockIdx.z;
  const float* X    = which == 0 ? Q  : which == 1 ? K  : V;
  const float* bias = which == 0 ? bq : which == 1 ? bk : bv;

  __shared__ __align__(16) float T[64 * 68];   // 17408 B, stride 68 words

  const int tid = threadIdx.x;
  const int w = tid >> 6, lane = tid & 63;
  const int l15 = lane & 15, quad = lane >> 4;
  const int mbase = blockIdx.y * 64;
  const int nfg   = blockIdx.x * 4;
  const int nn   = mbase >> 11;        // batch
  const int tile = blockIdx.y & 31;    // 64-row tile within batch

  half8 ahi[8], alo[8];
  {
    const float* xrow = X + (size_t)(mbase + w * 16 + l15) * H_DIM + quad * 8;
    #pragma unroll
    for (int s = 0; s < 8; ++s) {
      float4 a0 = *(const float4*)(xrow + s * 32);
      float4 a1 = *(const float4*)(xrow + s * 32 + 4);
      float xs[8] = {a0.x, a0.y, a0.z, a0.w, a1.x, a1.y, a1.z, a1.w};
      #pragma unroll
      for (int i = 0; i < 8; ++i) {
        _Float16 h = (_Float16)xs[i];
        ahi[s][i] = h;
        alo[s][i] = (_Float16)(xs[i] - (float)h);
      }
    }
  }

  f32x4 acc[4];
  #pragma unroll
  for (int f = 0; f < 4; ++f) acc[f] = (f32x4){0.f, 0.f, 0.f, 0.f};

  #pragma unroll
  for (int s = 0; s < 8; ++s) {
    const half8* ph = WpkHi + (((size_t)which * 8 + s) * 16 + nfg) * 64 + lane;
    const half8* pl = WpkLo + (((size_t)which * 8 + s) * 16 + nfg) * 64 + lane;
    #pragma unroll
    for (int f = 0; f < 4; ++f) {
      half8 BH = ph[f * 64];
      half8 BL = pl[f * 64];
      acc[f] = mfma16(ahi[s], BH, acc[f]);
      acc[f] = mfma16(ahi[s], BL, acc[f]);
      acc[f] = mfma16(alo[s], BH, acc[f]);
    }
  }

  // bias + relu (+ V last-key zero) -> LDS tile [t'][j]
  #pragma unroll
  for (int f = 0; f < 4; ++f) {
    float bj = bias[blockIdx.x * 64 + f * 16 + l15];
    #pragma unroll
    for (int r = 0; r < 4; ++r) {
      int row = w * 16 + quad * 4 + r;      // t' within tile
      float val = fmaxf(acc[f][r] + bj, 0.0f);
      if (which == 2 && ((mbase + row) & (TSEQ - 1)) == TSEQ - 1) val = 0.0f;
      T[row * 68 + f * 16 + l15] = val;
    }
  }
  __syncthreads();

  // fragment generation (2 heads per block: hs = 0,1 -> h = blockIdx.x*2+hs)
  if (which < 2) {
    const int fq = tid >> 6, lp = tid & 63;
    const int kdc = lp >> 4, krlo = lp & 15;
    const int row = fq * 16 + krlo;
    const float sc = (which == 0) ? QK2_SCALE : 1.0f;
    #pragma unroll
    for (int hs = 0; hs < 2; ++hs) {
      const float* p = &T[row * 68 + hs * 32 + kdc * 8];
      float4 a0 = *(const float4*)p;
      float4 a1 = *(const float4*)(p + 4);
      float xs[8] = {a0.x, a0.y, a0.z, a0.w, a1.x, a1.y, a1.z, a1.w};
      half8 hi, lo;
      #pragma unroll
      for (int i = 0; i < 8; ++i) {
        float x = xs[i] * sc;
        _Float16 h = (_Float16)x;
        hi[i] = h;
        lo[i] = (_Float16)(x - (float)h);
      }
      int hn = (blockIdx.x * 2 + hs) * NB + nn;
      size_t di = ((size_t)hn * 32 + tile) * 256 + tid;
      if (which == 0) { Gqhi[di] = hi; Gqlo[di] = lo; }
      else            { Gkhi[di] = hi; Gklo[di] = lo; }
    }
    // AmaskF: mask-row A-fragment, row0 = kmask as f16 (one block per tile)
    if (which == 1 && blockIdx.x == 0 && tid < 128) {
      int c = tid >> 6, lane2 = tid & 63;
      int quad2 = lane2 >> 4, l15b = lane2 & 15;
      half8 am;
      #pragma unroll
      for (int j = 0; j < 8; ++j)
        am[j] = (l15b == 0) ? (_Float16)kmask[(size_t)nn * TSEQ + tile * 64 + c * 32 + quad2 * 8 + j]
                            : (_Float16)0.0f;
      AmaskF[(((size_t)nn * 32 + tile) * 2 + c) * 64 + lane2] = am;
    }
  } else {
    const int top = tid >> 6, mid = (tid >> 4) & 3, low = tid & 15;
    const int c = top >> 1, hh = top & 1;
    const int trow0 = (c * 4 + mid) * 8;
    float km[8];
    #pragma unroll
    for (int j = 0; j < 8; ++j)
      km[j] = kmask[(size_t)nn * TSEQ + tile * 64 + trow0 + j];
    #pragma unroll
    for (int hs = 0; hs < 2; ++hs) {
      const int col = hs * 32 + hh * 16 + low;
      half8 v8;
      #pragma unroll
      for (int j = 0; j < 8; ++j)
        v8[j] = (_Float16)(T[(trow0 + j) * 68 + col] * km[j]);
      int hn = (blockIdx.x * 2 + hs) * NB + nn;
      Gv[((size_t)hn * 32 + tile) * 256 + tid] = v8;
    }
  }
}

// ---------------- MFMA flash attention + fused split-k combine/LN ----------------
// S^T = K·Q^T (rows=keys, cols=q). K-hi/lo, V, mask-frags staged once per block
// into double-buffered LDS; staging loads issue early, ds_write after PV.
// SPLIT=2: 1024 blocks = exactly 4 blocks/CU, 16 k-tiles each.
// After partial write, per-(n,qt) atomic counter; the 16th contributor (8 heads
// x 2 splits) performs the combine + LayerNorm for its 64 q-rows (Guideline 16:
// __threadfence release/acquire around device-scope atomicAdd).
__global__ __launch_bounds__(256, 4) void attn_kernel(
    const half8* __restrict__ Gqhi, const half8* __restrict__ Gqlo,
    const half8* __restrict__ Gkhi, const half8* __restrict__ Gklo,
    const half8* __restrict__ Gv, const half8* __restrict__ AmaskF,
    _Float16* __restrict__ Opf, float* __restrict__ Mp, float* __restrict__ Lp,
    const float* __restrict__ gamma, const float* __restrict__ beta,
    const float* __restrict__ qmask, int* __restrict__ ctr,
    float* __restrict__ out, float* __restrict__ wout) {
  __shared__ __align__(16) half8 KhB[2][256];           // 8 KB
  __shared__ __align__(16) half8 KlB[2][256];           // 8 KB
  __shared__ __align__(16) half8 VB[2][256];            // 8 KB
  __shared__ __align__(16) half8 AB[2][128];            // 4 KB
  __shared__ __align__(16) _Float16 Pbuf[4][16][72];    // [wave][q][key], stride 144B
  __shared__ int isLast;

  const int tid = threadIdx.x;
  const int w = tid >> 6, lane = tid & 63;
  const int l15 = lane & 15, quad = lane >> 4;

  const int b = blockIdx.x;
  const int g    = ((b & 7) << 1) | ((b >> 3) & 1);   // hn, XCD-pinned
  const int qt   = (b >> 4) & 31;
  const int sblk = b >> 9;                            // 0..1
  const int n = g & 1;

  const size_t fbase = (size_t)g * 32 * 256;
  const int tile0 = sblk * TILES_PER;

  // Q fragment (B-operand): col q = w*16 + l15, k(d) = quad*8..+8
  half8 qhi = Gqhi[fbase + (size_t)qt * 256 + w * 64 + lane];
  half8 qlo = Gqlo[fbase + (size_t)qt * 256 + w * 64 + lane];

  float m_q = -1.0e30f;
  f32x4 O0, O1, Ol;
  O0 = (f32x4){0.f, 0.f, 0.f, 0.f};
  O1 = (f32x4){0.f, 0.f, 0.f, 0.f};
  Ol = (f32x4){0.f, 0.f, 0.f, 0.f};

  const half8* gkh = Gkhi + fbase + (size_t)tile0 * 256;
  const half8* gkl = Gklo + fbase + (size_t)tile0 * 256;
  const half8* gvv = Gv   + fbase + (size_t)tile0 * 256;
  const half8* gam = AmaskF + (size_t)(n * 32 + tile0) * 128;

  // stage tile 0
  KhB[0][tid] = gkh[tid];
  KlB[0][tid] = gkl[tid];
  VB[0][tid]  = gvv[tid];
  if (tid < 128) AB[0][tid] = gam[tid];
  __syncthreads();

  #pragma unroll 2
  for (int tt = 0; tt < TILES_PER; ++tt) {
    const int cur = tt & 1, nxt = cur ^ 1;
    // issue next-tile loads early; ds_write after PV (latency hides under MFMA)
    half8 rkh, rkl, rv, ra;
    if (tt < TILES_PER - 1) {
      rkh = gkh[256 + tid];
      rkl = gkl[256 + tid];
      rv  = gvv[256 + tid];
      if (tid < 128) ra = gam[128 + tid];
    }

    // S^T = K Q^T (split-fp16): rows = keys f*16+quad*4+r, col = q = l15
    f32x4 S[4];
    __builtin_amdgcn_s_setprio(1);
    #pragma unroll
    for (int f = 0; f < 4; ++f) {
      half8 KH = KhB[cur][f * 64 + lane];
      half8 KL = KlB[cur][f * 64 + lane];
      f32x4 a = (f32x4){0.f, 0.f, 0.f, 0.f};
      a = mfma16(KL, qhi, a);
      a = mfma16(KH, qlo, a);
      a = mfma16(KH, qhi, a);
      S[f] = a;
    }
    __builtin_amdgcn_s_setprio(0);

    // per-q max: balanced tree + 2 shuffle stages
    float t0 = fmaxf(fmaxf(S[0][0], S[0][1]), fmaxf(S[0][2], S[0][3]));
    float t1 = fmaxf(fmaxf(S[1][0], S[1][1]), fmaxf(S[1][2], S[1][3]));
    float t2 = fmaxf(fmaxf(S[2][0], S[2][1]), fmaxf(S[2][2], S[2][3]));
    float t3 = fmaxf(fmaxf(S[3][0], S[3][1]), fmaxf(S[3][2], S[3][3]));
    float mx = fmaxf(fmaxf(t0, t1), fmaxf(t2, t3));
    mx = fmaxf(mx, __shfl_xor(mx, 16));
    mx = fmaxf(mx, __shfl_xor(mx, 32));

    float mnew = fmaxf(m_q, mx);
    float alpha = exp2fast(m_q - mnew);
    m_q = mnew;

    // P = exp2(S - m), pack pairs along keys -> Pbuf[q][key] (8B stores)
    #pragma unroll
    for (int f = 0; f < 4; ++f) {
      float p0 = exp2fast(S[f][0] - m_q);
      float p1 = exp2fast(S[f][1] - m_q);
      float p2 = exp2fast(S[f][2] - m_q);
      float p3 = exp2fast(S[f][3] - m_q);
      half2t a01 = pkrtz(p0, p1);
      half2t a23 = pkrtz(p2, p3);
      half4t pk4;
      pk4[0] = a01[0]; pk4[1] = a01[1]; pk4[2] = a23[0]; pk4[3] = a23[1];
      *(half4t*)&Pbuf[w][l15][f * 16 + quad * 4] = pk4;
    }
    #pragma unroll
    for (int r = 0; r < 4; ++r) { O0[r] *= alpha; O1[r] *= alpha; }
    Ol[0] *= alpha;
    // in-wave LDS RAW: drain DS queue before reading P as B-fragments
    asm volatile("s_waitcnt lgkmcnt(0)" ::: "memory");

    half8 am0 = AB[cur][lane];
    half8 am1 = AB[cur][64 + lane];
    const half8* vbuf = (const half8*)VB[cur];
    __builtin_amdgcn_s_setprio(1);
    #pragma unroll
    for (int c = 0; c < 2; ++c) {
      half8 pb = *(const half8*)&Pbuf[w][l15][c * 32 + quad * 8];
      O0 = mfma16(vbuf[(c * 2 + 0) * 64 + lane], pb, O0);
      O1 = mfma16(vbuf[(c * 2 + 1) * 64 + lane], pb, O1);
      Ol = mfma16(c == 0 ? am0 : am1, pb, Ol);
    }
    __builtin_amdgcn_s_setprio(0);

    if (tt < TILES_PER - 1) {
      KhB[nxt][tid] = rkh;
      KlB[nxt][tid] = rkl;
      VB[nxt][tid]  = rv;
      if (tid < 128) AB[nxt][tid] = ra;
    }
    __syncthreads();
    kh_advance:
    gkh += 256; gkl += 256; gvv += 256; gam += 128;
  }

  // partial epilogue: f16 partials (d = quad*4..+4 and +16), m/l from quad 0
  {
    int q = qt * 64 + w * 16 + l15;
    size_t idx = ((size_t)(sblk * 16 + g) * TSEQ + q) * DHEAD;
    half4t o0 = {(_Float16)O0[0], (_Float16)O0[1], (_Float16)O0[2], (_Float16)O0[3]};
    half4t o1 = {(_Float16)O1[0], (_Float16)O1[1], (_Float16)O1[2], (_Float16)O1[3]};
    *(half4t*)&Opf[idx + quad * 4]      = o0;
    *(half4t*)&Opf[idx + 16 + quad * 4] = o1;
    if (quad == 0) {
      Mp[(size_t)(sblk * 16 + g) * TSEQ + q] = m_q;
      Lp[(size_t)(sblk * 16 + g) * TSEQ + q] = Ol[0];
    }
  }

  // ---- split-k combine + LayerNorm, done by the last contributor ----
  __syncthreads();                     // drains vmcnt: partials are in L2
  if (tid == 0) {
    __threadfence();                   // release: publish partials device-wide
    int old = atomicAdd(&ctr[n * 32 + qt], 1);
    isLast = (old == 2 * NHEAD - 1);   // 16 contributors per (n,qt)
  }
  __syncthreads();
  if (!isLast) return;
  __threadfence();                     // acquire: invalidate stale cache lines

  const int hh2 = lane >> 3;                // head 0..7
  const int hn2 = hh2 * NB + n;
  const int dbase = (lane & 7) * 4;
  const float4 gma = *(const float4*)(gamma + lane * 4);
  const float4 bta = *(const float4*)(beta + lane * 4);
  for (int r = 0; r < 16; ++r) {
    const int q = qt * 64 + w * 16 + r;
    const int row = n * TSEQ + q;
    float ms[SPLIT], ls[SPLIT];
    half4t Pp[SPLIT];
    #pragma unroll
    for (int i = 0; i < SPLIT; ++i) {
      size_t si = (size_t)(i * 16 + hn2) * TSEQ + q;
      Pp[i] = *(const half4t*)&Opf[si * DHEAD + dbase];
      ms[i] = Mp[si];
      ls[i] = Lp[si];
    }
    float mmax = ms[0];
    #pragma unroll
    for (int i = 1; i < SPLIT; ++i) mmax = fmaxf(mmax, ms[i]);
    float denom = 0.f, aa[SPLIT];
    #pragma unroll
    for (int i = 0; i < SPLIT; ++i) { aa[i] = exp2fast(ms[i] - mmax); denom += ls[i] * aa[i]; }
    float qm = qmask[row];
    float inv = qm / denom;

    float4 x = make_float4(0.f, 0.f, 0.f, 0.f);
    #pragma unroll
    for (int i = 0; i < SPLIT; ++i) {
      x.x += (float)Pp[i][0] * aa[i]; x.y += (float)Pp[i][1] * aa[i];
      x.z += (float)Pp[i][2] * aa[i]; x.w += (float)Pp[i][3] * aa[i];
    }
    x.x *= inv; x.y *= inv; x.z *= inv; x.w *= inv;

    float s = x.x + x.y + x.z + x.w;
    #pragma unroll
    for (int off = 32; off > 0; off >>= 1) s += __shfl_xor(s, off);
    float mu = s * (1.0f / H_DIM);
    float dx0 = x.x - mu, dx1 = x.y - mu, dx2 = x.z - mu, dx3 = x.w - mu;
    float sq = dx0 * dx0 + dx1 * dx1 + dx2 * dx2 + dx3 * dx3;
    #pragma unroll
    for (int off = 32; off > 0; off >>= 1) sq += __shfl_xor(sq, off);
    float rstd = rsqrtf(sq * (1.0f / H_DIM) + LN_EPS);
    float4 y;
    y.x = dx0 * rstd * gma.x + bta.x;
    y.y = dx1 * rstd * gma.y + bta.y;
    y.z = dx2 * rstd * gma.z + bta.z;
    y.w = dx3 * rstd * gma.w + bta.w;
    *(float4*)(out + (size_t)row * H_DIM + lane * 4) = y;
    if (lane == 0) wout[row] = qm * (1.0f / TSEQ);
  }
}

extern "C" void kernel_launch(void* const* d_in, const int* in_sizes, int n_in,
                              void* d_out, int out_size, void* d_ws, size_t ws_size,
                              hipStream_t stream) {
  const float* Q  = (const float*)d_in[0];
  const float* K  = (const float*)d_in[1];
  const float* V  = (const float*)d_in[2];
  const float* Wq = (const float*)d_in[3];
  const float* bq = (const float*)d_in[4];
  const float* Wk = (const float*)d_in[5];
  const float* bk = (const float*)d_in[6];
  const float* Wv = (const float*)d_in[7];
  const float* bv = (const float*)d_in[8];
  const float* gamma = (const float*)d_in[9];
  const float* beta  = (const float*)d_in[10];

  char* ws = (char*)d_ws;
  const size_t NFRAG = (size_t)16 * 32 * 256;            // frags per array
  _Float16* Opf = (_Float16*)ws;                          // [SPLIT][16][TSEQ][32] f16
  half8* Gqhi = (half8*)(ws + (size_t)SPLIT * 16 * TSEQ * DHEAD * 2);
  half8* Gqlo = Gqhi + NFRAG;
  half8* Gkhi = Gqlo + NFRAG;
  half8* Gklo = Gkhi + NFRAG;
  half8* Gv   = Gklo + NFRAG;
  float* Mp = (float*)(Gv + NFRAG);                       // [SPLIT][16][TSEQ]
  float* Lp = Mp + SPLIT * 16 * TSEQ;
  float* qmask = Lp + SPLIT * 16 * TSEQ;
  float* kmask = qmask + NB * TSEQ;
  half8* WpkHi = (half8*)(kmask + NB * TSEQ);
  half8* WpkLo = WpkHi + 24576;
  half8* AmaskF = WpkLo + 24576;                          // [NB][32][2][64]
  int* ctr = (int*)(AmaskF + (size_t)NB * 32 * 2 * 64);   // 64 counters

  float* out  = (float*)d_out;
  float* wout = out + (size_t)NB * TSEQ * H_DIM;

  hipLaunchKernelGGL(setup_kernel, dim3(2048 + 96), dim3(256), 0, stream,
                     Q, K, Wq, Wk, Wv, qmask, kmask, WpkHi, WpkLo, ctr);
  hipLaunchKernelGGL(proj_kernel, dim3(H_DIM / 64, NB * TSEQ / 64, 3), dim3(256), 0, stream,
                     Q, K, V, bq, bk, bv, WpkHi, WpkLo, kmask,
                     Gqhi, Gqlo, Gkhi, Gklo, Gv, AmaskF);
  hipLaunchKernelGGL(attn_kernel, dim3(16 * 32 * SPLIT), dim3(256), 0, stream,
                     Gqhi, Gqlo, Gkhi, Gklo, Gv, AmaskF, Opf, Mp, Lp,
                     gamma, beta, qmask, ctr, out, wout);
}

// Round 3
// 127.797 us; speedup vs baseline: 1.4455x; 1.4455x over previous
//
#include <hip/hip_runtime.h>
#include <math.h>

// Problem constants (fixed by reference)
#define H_DIM 256
#define NHEAD 8
#define DHEAD 32
#define NB 2
#define TSEQ 2048
#define LN_EPS 1e-5f

// softmax in exp2 domain: logit2 = s * (100/sqrt(32)) * log2(e).
// QK2_SCALE is folded into the packed Q fragments (proj frag-gen).
#define QK2_SCALE 25.503486f
#define SPLIT 2                         // key-split factor
#define TILES_PER (TSEQ / 64 / SPLIT)   // 16 k-tiles per block

typedef _Float16 half8 __attribute__((ext_vector_type(8)));
typedef _Float16 half4t __attribute__((ext_vector_type(4)));
typedef _Float16 half2t __attribute__((ext_vector_type(2)));
typedef float f32x4 __attribute__((ext_vector_type(4)));

__device__ __forceinline__ f32x4 mfma16(half8 a, half8 b, f32x4 c) {
  return __builtin_amdgcn_mfma_f32_16x16x32_f16(a, b, c, 0, 0, 0);
}
__device__ __forceinline__ float exp2fast(float x) {
  return __builtin_amdgcn_exp2f(x);
}
__device__ __forceinline__ half2t pkrtz(float a, float b) {
  return __builtin_bit_cast(half2t, __builtin_amdgcn_cvt_pkrtz(a, b));
}

// ---------------- fused masks + W pre-pack ----------------
// blocks < 2048: qmask/kmask = sign(sum|x|) per row of Q/K.
// blocks >= 2048: W fp32 -> hi/lo f16 B-fragment layout (no mask dependency).
__global__ __launch_bounds__(256) void setup_kernel(
    const float* __restrict__ Q, const float* __restrict__ K,
    const float* __restrict__ Wq, const float* __restrict__ Wk, const float* __restrict__ Wv,
    float* __restrict__ qmask, float* __restrict__ kmask,
    half8* __restrict__ WpkHi, half8* __restrict__ WpkLo) {
  const int tid = threadIdx.x;
  if (blockIdx.x < 2048) {
    const int wid = tid >> 6, lane = tid & 63;
    int row = blockIdx.x * 4 + wid;
    const int total_q = NB * TSEQ;
    const float* src;
    float* dst;
    if (row < total_q) { src = Q + (size_t)row * H_DIM; dst = qmask + row; }
    else               { src = K + (size_t)(row - total_q) * H_DIM; dst = kmask + (row - total_q); }
    float4 v = *(const float4*)(src + lane * 4);
    float s = fabsf(v.x) + fabsf(v.y) + fabsf(v.z) + fabsf(v.w);
    #pragma unroll
    for (int off = 32; off > 0; off >>= 1) s += __shfl_xor(s, off);
    if (lane == 0) *dst = (s != 0.0f) ? 1.0f : 0.0f;
    return;
  }
  int slot = (blockIdx.x - 2048) * 256 + tid;   // 0..24575
  int lane = slot & 63;
  int fg = (slot >> 6) & 15;
  int s  = (slot >> 10) & 7;
  int which = slot >> 13;
  const float* W = which == 0 ? Wq : which == 1 ? Wk : Wv;
  int j  = fg * 16 + (lane & 15);
  int kb = s * 32 + (lane >> 4) * 8;
  half8 hi, lo;
  #pragma unroll
  for (int jj = 0; jj < 8; ++jj) {
    float x = W[(size_t)(kb + jj) * H_DIM + j];
    _Float16 h = (_Float16)x;
    hi[jj] = h;
    lo[jj] = (_Float16)(x - (float)h);
  }
  WpkHi[slot] = hi;
  WpkLo[slot] = lo;
}

// ---------------- fused projection + frag repack (+ AmaskF emit) ----------------
// relu(X@W+b) via split-fp16 MFMA; result tile (64 t x 64 j = 2 heads) goes
// through LDS transpose and exits directly as MFMA fragment arrays:
//   Q/K: hi/lo split-f16 frags (Q pre-scaled by QK2_SCALE)
//   V:   transposed f16 frags, kmask- and t==2047-zeroed.
// which==1, x==0 blocks additionally emit AmaskF (mask-row A-fragments).
__global__ __launch_bounds__(256) void proj_kernel(
    const float* __restrict__ Q, const float* __restrict__ K, const float* __restrict__ V,
    const float* __restrict__ bq, const float* __restrict__ bk, const float* __restrict__ bv,
    const half8* __restrict__ WpkHi, const half8* __restrict__ WpkLo,
    const float* __restrict__ kmask,
    half8* __restrict__ Gqhi, half8* __restrict__ Gqlo,
    half8* __restrict__ Gkhi, half8* __restrict__ Gklo, half8* __restrict__ Gv,
    half8* __restrict__ AmaskF) {
  const int which = blockIdx.z;
  const float* X    = which == 0 ? Q  : which == 1 ? K  : V;
  const float* bias = which == 0 ? bq : which == 1 ? bk : bv;

  __shared__ __align__(16) float T[64 * 68];   // 17408 B, stride 68 words

  const int tid = threadIdx.x;
  const int w = tid >> 6, lane = tid & 63;
  const int l15 = lane & 15, quad = lane >> 4;
  const int mbase = blockIdx.y * 64;
  const int nfg   = blockIdx.x * 4;
  const int nn   = mbase >> 11;        // batch
  const int tile = blockIdx.y & 31;    // 64-row tile within batch

  half8 ahi[8], alo[8];
  {
    const float* xrow = X + (size_t)(mbase + w * 16 + l15) * H_DIM + quad * 8;
    #pragma unroll
    for (int s = 0; s < 8; ++s) {
      float4 a0 = *(const float4*)(xrow + s * 32);
      float4 a1 = *(const float4*)(xrow + s * 32 + 4);
      float xs[8] = {a0.x, a0.y, a0.z, a0.w, a1.x, a1.y, a1.z, a1.w};
      #pragma unroll
      for (int i = 0; i < 8; ++i) {
        _Float16 h = (_Float16)xs[i];
        ahi[s][i] = h;
        alo[s][i] = (_Float16)(xs[i] - (float)h);
      }
    }
  }

  f32x4 acc[4];
  #pragma unroll
  for (int f = 0; f < 4; ++f) acc[f] = (f32x4){0.f, 0.f, 0.f, 0.f};

  #pragma unroll
  for (int s = 0; s < 8; ++s) {
    const half8* ph = WpkHi + (((size_t)which * 8 + s) * 16 + nfg) * 64 + lane;
    const half8* pl = WpkLo + (((size_t)which * 8 + s) * 16 + nfg) * 64 + lane;
    #pragma unroll
    for (int f = 0; f < 4; ++f) {
      half8 BH = ph[f * 64];
      half8 BL = pl[f * 64];
      acc[f] = mfma16(ahi[s], BH, acc[f]);
      acc[f] = mfma16(ahi[s], BL, acc[f]);
      acc[f] = mfma16(alo[s], BH, acc[f]);
    }
  }

  // bias + relu (+ V last-key zero) -> LDS tile [t'][j]
  #pragma unroll
  for (int f = 0; f < 4; ++f) {
    float bj = bias[blockIdx.x * 64 + f * 16 + l15];
    #pragma unroll
    for (int r = 0; r < 4; ++r) {
      int row = w * 16 + quad * 4 + r;      // t' within tile
      float val = fmaxf(acc[f][r] + bj, 0.0f);
      if (which == 2 && ((mbase + row) & (TSEQ - 1)) == TSEQ - 1) val = 0.0f;
      T[row * 68 + f * 16 + l15] = val;
    }
  }
  __syncthreads();

  // fragment generation (2 heads per block: hs = 0,1 -> h = blockIdx.x*2+hs)
  if (which < 2) {
    const int fq = tid >> 6, lp = tid & 63;
    const int kdc = lp >> 4, krlo = lp & 15;
    const int row = fq * 16 + krlo;
    const float sc = (which == 0) ? QK2_SCALE : 1.0f;
    #pragma unroll
    for (int hs = 0; hs < 2; ++hs) {
      const float* p = &T[row * 68 + hs * 32 + kdc * 8];
      float4 a0 = *(const float4*)p;
      float4 a1 = *(const float4*)(p + 4);
      float xs[8] = {a0.x, a0.y, a0.z, a0.w, a1.x, a1.y, a1.z, a1.w};
      half8 hi, lo;
      #pragma unroll
      for (int i = 0; i < 8; ++i) {
        float x = xs[i] * sc;
        _Float16 h = (_Float16)x;
        hi[i] = h;
        lo[i] = (_Float16)(x - (float)h);
      }
      int hn = (blockIdx.x * 2 + hs) * NB + nn;
      size_t di = ((size_t)hn * 32 + tile) * 256 + tid;
      if (which == 0) { Gqhi[di] = hi; Gqlo[di] = lo; }
      else            { Gkhi[di] = hi; Gklo[di] = lo; }
    }
    // AmaskF: mask-row A-fragment, row0 = kmask as f16 (one block per tile)
    if (which == 1 && blockIdx.x == 0 && tid < 128) {
      int c = tid >> 6, lane2 = tid & 63;
      int quad2 = lane2 >> 4, l15b = lane2 & 15;
      half8 am;
      #pragma unroll
      for (int j = 0; j < 8; ++j)
        am[j] = (l15b == 0) ? (_Float16)kmask[(size_t)nn * TSEQ + tile * 64 + c * 32 + quad2 * 8 + j]
                            : (_Float16)0.0f;
      AmaskF[(((size_t)nn * 32 + tile) * 2 + c) * 64 + lane2] = am;
    }
  } else {
    const int top = tid >> 6, mid = (tid >> 4) & 3, low = tid & 15;
    const int c = top >> 1, hh = top & 1;
    const int trow0 = (c * 4 + mid) * 8;
    float km[8];
    #pragma unroll
    for (int j = 0; j < 8; ++j)
      km[j] = kmask[(size_t)nn * TSEQ + tile * 64 + trow0 + j];
    #pragma unroll
    for (int hs = 0; hs < 2; ++hs) {
      const int col = hs * 32 + hh * 16 + low;
      half8 v8;
      #pragma unroll
      for (int j = 0; j < 8; ++j)
        v8[j] = (_Float16)(T[(trow0 + j) * 68 + col] * km[j]);
      int hn = (blockIdx.x * 2 + hs) * NB + nn;
      Gv[((size_t)hn * 32 + tile) * 256 + tid] = v8;
    }
  }
}

// ---------------- MFMA flash attention, transposed-S, key-split x2 ----------------
// S^T = K·Q^T (rows=keys, cols=q). K-hi/lo, V, and mask-frags are staged ONCE
// per block into double-buffered LDS; staging loads issue early (T14),
// ds_write after PV. SPLIT=2: 1024 blocks = one full 4-blocks/CU generation,
// halved partial traffic and halved block prologue/epilogue count vs SPLIT=4.
// No device-scope fences here (R2 lesson: per-block agent fences = L2
// writeback storms; the kernel-launch boundary orders partials for free).
__global__ __launch_bounds__(256, 4) void attn_kernel(
    const half8* __restrict__ Gqhi, const half8* __restrict__ Gqlo,
    const half8* __restrict__ Gkhi, const half8* __restrict__ Gklo,
    const half8* __restrict__ Gv, const half8* __restrict__ AmaskF,
    _Float16* __restrict__ Opf, float* __restrict__ Mp, float* __restrict__ Lp) {
  __shared__ __align__(16) half8 KhB[2][256];           // 8 KB
  __shared__ __align__(16) half8 KlB[2][256];           // 8 KB
  __shared__ __align__(16) half8 VB[2][256];            // 8 KB
  __shared__ __align__(16) half8 AB[2][128];            // 4 KB
  __shared__ __align__(16) _Float16 Pbuf[4][16][72];    // [wave][q][key], stride 144B

  const int tid = threadIdx.x;
  const int w = tid >> 6, lane = tid & 63;
  const int l15 = lane & 15, quad = lane >> 4;

  const int b = blockIdx.x;
  const int g    = ((b & 7) << 1) | ((b >> 3) & 1);   // hn, XCD-pinned
  const int qt   = (b >> 4) & 31;
  const int sblk = b >> 9;                            // 0..1
  const int n = g & 1;

  const size_t fbase = (size_t)g * 32 * 256;
  const int tile0 = sblk * TILES_PER;

  // Q fragment (B-operand): col q = w*16 + l15, k(d) = quad*8..+8
  half8 qhi = Gqhi[fbase + (size_t)qt * 256 + w * 64 + lane];
  half8 qlo = Gqlo[fbase + (size_t)qt * 256 + w * 64 + lane];

  float m_q = -1.0e30f;
  f32x4 O0, O1, Ol;
  O0 = (f32x4){0.f, 0.f, 0.f, 0.f};
  O1 = (f32x4){0.f, 0.f, 0.f, 0.f};
  Ol = (f32x4){0.f, 0.f, 0.f, 0.f};

  const half8* gkh = Gkhi + fbase + (size_t)tile0 * 256;
  const half8* gkl = Gklo + fbase + (size_t)tile0 * 256;
  const half8* gvv = Gv   + fbase + (size_t)tile0 * 256;
  const half8* gam = AmaskF + (size_t)(n * 32 + tile0) * 128;

  // stage tile 0
  KhB[0][tid] = gkh[tid];
  KlB[0][tid] = gkl[tid];
  VB[0][tid]  = gvv[tid];
  if (tid < 128) AB[0][tid] = gam[tid];
  __syncthreads();

  #pragma unroll
  for (int tt = 0; tt < TILES_PER; ++tt) {
    const int cur = tt & 1, nxt = cur ^ 1;
    // issue next-tile loads early; ds_write after PV (latency hides under MFMA)
    half8 rkh, rkl, rv, ra;
    if (tt < TILES_PER - 1) {
      rkh = gkh[(tt + 1) * 256 + tid];
      rkl = gkl[(tt + 1) * 256 + tid];
      rv  = gvv[(tt + 1) * 256 + tid];
      if (tid < 128) ra = gam[(tt + 1) * 128 + tid];
    }

    // S^T = K Q^T (split-fp16): rows = keys f*16+quad*4+r, col = q = l15
    f32x4 S[4];
    #pragma unroll
    for (int f = 0; f < 4; ++f) {
      half8 KH = KhB[cur][f * 64 + lane];
      half8 KL = KlB[cur][f * 64 + lane];
      f32x4 a = (f32x4){0.f, 0.f, 0.f, 0.f};
      a = mfma16(KL, qhi, a);
      a = mfma16(KH, qlo, a);
      a = mfma16(KH, qhi, a);
      S[f] = a;
    }

    // per-q max: balanced tree + 2 shuffle stages
    float t0 = fmaxf(fmaxf(S[0][0], S[0][1]), fmaxf(S[0][2], S[0][3]));
    float t1 = fmaxf(fmaxf(S[1][0], S[1][1]), fmaxf(S[1][2], S[1][3]));
    float t2 = fmaxf(fmaxf(S[2][0], S[2][1]), fmaxf(S[2][2], S[2][3]));
    float t3 = fmaxf(fmaxf(S[3][0], S[3][1]), fmaxf(S[3][2], S[3][3]));
    float mx = fmaxf(fmaxf(t0, t1), fmaxf(t2, t3));
    mx = fmaxf(mx, __shfl_xor(mx, 16));
    mx = fmaxf(mx, __shfl_xor(mx, 32));

    float mnew = fmaxf(m_q, mx);
    float alpha = exp2fast(m_q - mnew);
    m_q = mnew;

    // P = exp2(S - m), pack pairs along keys -> Pbuf[q][key] (8B stores)
    #pragma unroll
    for (int f = 0; f < 4; ++f) {
      float p0 = exp2fast(S[f][0] - m_q);
      float p1 = exp2fast(S[f][1] - m_q);
      float p2 = exp2fast(S[f][2] - m_q);
      float p3 = exp2fast(S[f][3] - m_q);
      half2t a01 = pkrtz(p0, p1);
      half2t a23 = pkrtz(p2, p3);
      half4t pk4;
      pk4[0] = a01[0]; pk4[1] = a01[1]; pk4[2] = a23[0]; pk4[3] = a23[1];
      *(half4t*)&Pbuf[w][l15][f * 16 + quad * 4] = pk4;
    }
    #pragma unroll
    for (int r = 0; r < 4; ++r) { O0[r] *= alpha; O1[r] *= alpha; }
    Ol[0] *= alpha;
    // in-wave LDS RAW: drain DS queue before reading P as B-fragments
    asm volatile("s_waitcnt lgkmcnt(0)" ::: "memory");

    half8 am0 = AB[cur][lane];
    half8 am1 = AB[cur][64 + lane];
    const half8* vbuf = (const half8*)VB[cur];
    #pragma unroll
    for (int c = 0; c < 2; ++c) {
      half8 pb = *(const half8*)&Pbuf[w][l15][c * 32 + quad * 8];
      O0 = mfma16(vbuf[(c * 2 + 0) * 64 + lane], pb, O0);
      O1 = mfma16(vbuf[(c * 2 + 1) * 64 + lane], pb, O1);
      Ol = mfma16(c == 0 ? am0 : am1, pb, Ol);
    }

    if (tt < TILES_PER - 1) {
      KhB[nxt][tid] = rkh;
      KlB[nxt][tid] = rkl;
      VB[nxt][tid]  = rv;
      if (tid < 128) AB[nxt][tid] = ra;
    }
    __syncthreads();
  }

  // epilogue: f16 partials (d = quad*4..+4 and +16), m/l from quad 0
  {
    int q = qt * 64 + w * 16 + l15;
    size_t idx = ((size_t)(sblk * 16 + g) * TSEQ + q) * DHEAD;
    half4t o0 = {(_Float16)O0[0], (_Float16)O0[1], (_Float16)O0[2], (_Float16)O0[3]};
    half4t o1 = {(_Float16)O1[0], (_Float16)O1[1], (_Float16)O1[2], (_Float16)O1[3]};
    *(half4t*)&Opf[idx + quad * 4]      = o0;
    *(half4t*)&Opf[idx + 16 + quad * 4] = o1;
    if (quad == 0) {
      Mp[(size_t)(sblk * 16 + g) * TSEQ + q] = m_q;
      Lp[(size_t)(sblk * 16 + g) * TSEQ + q] = Ol[0];
    }
  }
}

// ---------------- fused 2-way combine + layernorm + weight ----------------
__global__ __launch_bounds__(256) void ln_kernel(
    const _Float16* __restrict__ Opf, const float* __restrict__ Mp, const float* __restrict__ Lp,
    const float* __restrict__ gamma, const float* __restrict__ beta,
    const float* __restrict__ qmask,
    float* __restrict__ out, float* __restrict__ wout) {
  const int wid = threadIdx.x >> 6, lane = threadIdx.x & 63;
  const int row = blockIdx.x * 4 + wid;
  const int n = row >> 11, q = row & (TSEQ - 1);
  const int hh = lane >> 3;
  const int hn = hh * NB + n;
  const int dbase = (lane & 7) * 4;

  float m[SPLIT], l[SPLIT];
  half4t P[SPLIT];
  #pragma unroll
  for (int i = 0; i < SPLIT; ++i) {
    size_t si = (size_t)(i * 16 + hn) * TSEQ + q;
    P[i] = *(const half4t*)&Opf[si * DHEAD + dbase];
    m[i] = Mp[si];
    l[i] = Lp[si];
  }
  float mm = m[0];
  #pragma unroll
  for (int i = 1; i < SPLIT; ++i) mm = fmaxf(mm, m[i]);
  float denom = 0.f;
  float a[SPLIT];
  #pragma unroll
  for (int i = 0; i < SPLIT; ++i) { a[i] = exp2fast(m[i] - mm); denom += l[i] * a[i]; }
  float qm = qmask[row];
  float inv = qm / denom;

  float4 x = make_float4(0.f, 0.f, 0.f, 0.f);
  #pragma unroll
  for (int i = 0; i < SPLIT; ++i) {
    x.x += (float)P[i][0] * a[i]; x.y += (float)P[i][1] * a[i];
    x.z += (float)P[i][2] * a[i]; x.w += (float)P[i][3] * a[i];
  }
  x.x *= inv; x.y *= inv; x.z *= inv; x.w *= inv;

  float s = x.x + x.y + x.z + x.w;
  #pragma unroll
  for (int off = 32; off > 0; off >>= 1) s += __shfl_xor(s, off);
  float mu = s * (1.0f / H_DIM);
  float dx0 = x.x - mu, dx1 = x.y - mu, dx2 = x.z - mu, dx3 = x.w - mu;
  float sq = dx0 * dx0 + dx1 * dx1 + dx2 * dx2 + dx3 * dx3;
  #pragma unroll
  for (int off = 32; off > 0; off >>= 1) sq += __shfl_xor(sq, off);
  float rstd = rsqrtf(sq * (1.0f / H_DIM) + LN_EPS);
  float4 g = *(const float4*)(gamma + lane * 4);
  float4 bb = *(const float4*)(beta + lane * 4);
  float4 y;
  y.x = dx0 * rstd * g.x + bb.x;
  y.y = dx1 * rstd * g.y + bb.y;
  y.z = dx2 * rstd * g.z + bb.z;
  y.w = dx3 * rstd * g.w + bb.w;
  *(float4*)(out + (size_t)row * H_DIM + lane * 4) = y;
  if (lane == 0) wout[row] = qm * (1.0f / TSEQ);
}

extern "C" void kernel_launch(void* const* d_in, const int* in_sizes, int n_in,
                              void* d_out, int out_size, void* d_ws, size_t ws_size,
                              hipStream_t stream) {
  const float* Q  = (const float*)d_in[0];
  const float* K  = (const float*)d_in[1];
  const float* V  = (const float*)d_in[2];
  const float* Wq = (const float*)d_in[3];
  const float* bq = (const float*)d_in[4];
  const float* Wk = (const float*)d_in[5];
  const float* bk = (const float*)d_in[6];
  const float* Wv = (const float*)d_in[7];
  const float* bv = (const float*)d_in[8];
  const float* gamma = (const float*)d_in[9];
  const float* beta  = (const float*)d_in[10];

  char* ws = (char*)d_ws;
  const size_t NFRAG = (size_t)16 * 32 * 256;            // frags per array
  _Float16* Opf = (_Float16*)ws;                          // [SPLIT][16][TSEQ][32] f16
  half8* Gqhi = (half8*)(ws + (size_t)SPLIT * 16 * TSEQ * DHEAD * 2);
  half8* Gqlo = Gqhi + NFRAG;
  half8* Gkhi = Gqlo + NFRAG;
  half8* Gklo = Gkhi + NFRAG;
  half8* Gv   = Gklo + NFRAG;
  float* Mp = (float*)(Gv + NFRAG);                       // [SPLIT][16][TSEQ]
  float* Lp = Mp + SPLIT * 16 * TSEQ;
  float* qmask = Lp + SPLIT * 16 * TSEQ;
  float* kmask = qmask + NB * TSEQ;
  half8* WpkHi = (half8*)(kmask + NB * TSEQ);
  half8* WpkLo = WpkHi + 24576;
  half8* AmaskF = WpkLo + 24576;                          // [NB][32][2][64]

  float* out  = (float*)d_out;
  float* wout = out + (size_t)NB * TSEQ * H_DIM;

  hipLaunchKernelGGL(setup_kernel, dim3(2048 + 96), dim3(256), 0, stream,
                     Q, K, Wq, Wk, Wv, qmask, kmask, WpkHi, WpkLo);
  hipLaunchKernelGGL(proj_kernel, dim3(H_DIM / 64, NB * TSEQ / 64, 3), dim3(256), 0, stream,
                     Q, K, V, bq, bk, bv, WpkHi, WpkLo, kmask,
                     Gqhi, Gqlo, Gkhi, Gklo, Gv, AmaskF);
  hipLaunchKernelGGL(attn_kernel, dim3(16 * 32 * SPLIT), dim3(256), 0, stream,
                     Gqhi, Gqlo, Gkhi, Gklo, Gv, AmaskF, Opf, Mp, Lp);
  hipLaunchKernelGGL(ln_kernel, dim3(NB * TSEQ / 4), dim3(256), 0, stream,
                     Opf, Mp, Lp, gamma, beta, qmask, out, wout);
}

// Round 5
// 127.266 us; speedup vs baseline: 1.4515x; 1.0042x over previous
//
#include <hip/hip_runtime.h>
#include <math.h>

// Problem constants (fixed by reference)
#define H_DIM 256
#define NHEAD 8
#define DHEAD 32
#define NB 2
#define TSEQ 2048
#define LN_EPS 1e-5f

// softmax in exp2 domain: logit2 = s * (100/sqrt(32)) * log2(e).
// QK2_SCALE is folded into the packed Q fragments (proj frag-gen).
#define QK2_SCALE 25.503486f
#define SPLIT 2                         // key-split factor
#define TILES_PER (TSEQ / 64 / SPLIT)   // 16 k-tiles per block

typedef _Float16 half8 __attribute__((ext_vector_type(8)));
typedef _Float16 half4t __attribute__((ext_vector_type(4)));
typedef _Float16 half2t __attribute__((ext_vector_type(2)));
typedef float f32x4 __attribute__((ext_vector_type(4)));

__device__ __forceinline__ f32x4 mfma16(half8 a, half8 b, f32x4 c) {
  return __builtin_amdgcn_mfma_f32_16x16x32_f16(a, b, c, 0, 0, 0);
}
__device__ __forceinline__ float exp2fast(float x) {
  return __builtin_amdgcn_exp2f(x);
}
__device__ __forceinline__ half2t pkrtz(float a, float b) {
  return __builtin_bit_cast(half2t, __builtin_amdgcn_cvt_pkrtz(a, b));
}

// ---------------- kmask + W pre-pack ----------------
// blocks < 1024: kmask = sign(sum|x|) per row of K (4 rows/block).
// blocks >= 1024: W fp32 -> hi/lo f16 B-fragment layout.
// qmask moved into proj_kernel (Q rows are already loaded there in fp32;
// the old mask kernel's 4 MB Q re-read was pure waste).
__global__ __launch_bounds__(256) void pack_mask_kernel(
    const float* __restrict__ K,
    const float* __restrict__ Wq, const float* __restrict__ Wk, const float* __restrict__ Wv,
    float* __restrict__ kmask,
    half8* __restrict__ WpkHi, half8* __restrict__ WpkLo) {
  const int tid = threadIdx.x;
  if (blockIdx.x < 1024) {
    const int wid = tid >> 6, lane = tid & 63;
    int row = blockIdx.x * 4 + wid;                 // 0..4095 (NB*TSEQ K rows)
    const float* src = K + (size_t)row * H_DIM;
    float4 v = *(const float4*)(src + lane * 4);
    float s = fabsf(v.x) + fabsf(v.y) + fabsf(v.z) + fabsf(v.w);
    #pragma unroll
    for (int off = 32; off > 0; off >>= 1) s += __shfl_xor(s, off);
    if (lane == 0) kmask[row] = (s != 0.0f) ? 1.0f : 0.0f;
    return;
  }
  int slot = (blockIdx.x - 1024) * 256 + tid;   // 0..24575
  int lane = slot & 63;
  int fg = (slot >> 6) & 15;
  int s  = (slot >> 10) & 7;
  int which = slot >> 13;
  const float* W = which == 0 ? Wq : which == 1 ? Wk : Wv;
  int j  = fg * 16 + (lane & 15);
  int kb = s * 32 + (lane >> 4) * 8;
  half8 hi, lo;
  #pragma unroll
  for (int jj = 0; jj < 8; ++jj) {
    float x = W[(size_t)(kb + jj) * H_DIM + j];
    _Float16 h = (_Float16)x;
    hi[jj] = h;
    lo[jj] = (_Float16)(x - (float)h);
  }
  WpkHi[slot] = hi;
  WpkLo[slot] = lo;
}

// ---------------- fused projection + frag repack (+ AmaskF/qmask emit) ---------
// relu(X@W+b) via split-fp16 MFMA; result tile (64 t x 64 j = 2 heads) goes
// through LDS transpose and exits directly as MFMA fragment arrays:
//   Q/K: hi/lo split-f16 frags (Q pre-scaled by QK2_SCALE)
//   V:   transposed f16 frags, kmask- and t==2047-zeroed.
// which==0, x==0 blocks emit qmask from the fp32 A-data already in registers
// (cross-quad shuffle reduction). which==1, x==0 blocks emit AmaskF.
__global__ __launch_bounds__(256) void proj_kernel(
    const float* __restrict__ Q, const float* __restrict__ K, const float* __restrict__ V,
    const float* __restrict__ bq, const float* __restrict__ bk, const float* __restrict__ bv,
    const half8* __restrict__ WpkHi, const half8* __restrict__ WpkLo,
    const float* __restrict__ kmask,
    half8* __restrict__ Gqhi, half8* __restrict__ Gqlo,
    half8* __restrict__ Gkhi, half8* __restrict__ Gklo, half8* __restrict__ Gv,
    half8* __restrict__ AmaskF, float* __restrict__ qmask) {
  const int which = blockIdx.z;
  const float* X    = which == 0 ? Q  : which == 1 ? K  : V;
  const float* bias = which == 0 ? bq : which == 1 ? bk : bv;

  __shared__ __align__(16) float T[64 * 68];   // 17408 B, stride 68 words

  const int tid = threadIdx.x;
  const int w = tid >> 6, lane = tid & 63;
  const int l15 = lane & 15, quad = lane >> 4;
  const int mbase = blockIdx.y * 64;
  const int nfg   = blockIdx.x * 4;
  const int nn   = mbase >> 11;        // batch
  const int tile = blockIdx.y & 31;    // 64-row tile within batch

  half8 ahi[8], alo[8];
  {
    const bool doqm = (which == 0) && (blockIdx.x == 0);
    float sabs = 0.0f;
    const float* xrow = X + (size_t)(mbase + w * 16 + l15) * H_DIM + quad * 8;
    #pragma unroll
    for (int s = 0; s < 8; ++s) {
      float4 a0 = *(const float4*)(xrow + s * 32);
      float4 a1 = *(const float4*)(xrow + s * 32 + 4);
      float xs[8] = {a0.x, a0.y, a0.z, a0.w, a1.x, a1.y, a1.z, a1.w};
      if (doqm) {
        #pragma unroll
        for (int i = 0; i < 8; ++i) sabs += fabsf(xs[i]);
      }
      #pragma unroll
      for (int i = 0; i < 8; ++i) {
        _Float16 h = (_Float16)xs[i];
        ahi[s][i] = h;
        alo[s][i] = (_Float16)(xs[i] - (float)h);
      }
    }
    if (doqm) {
      // reduce over the 4 quads holding this row's 4 column-chunks
      sabs += __shfl_xor(sabs, 16);
      sabs += __shfl_xor(sabs, 32);
      if (quad == 0) qmask[mbase + w * 16 + l15] = (sabs != 0.0f) ? 1.0f : 0.0f;
    }
  }

  f32x4 acc[4];
  #pragma unroll
  for (int f = 0; f < 4; ++f) acc[f] = (f32x4){0.f, 0.f, 0.f, 0.f};

  #pragma unroll
  for (int s = 0; s < 8; ++s) {
    const half8* ph = WpkHi + (((size_t)which * 8 + s) * 16 + nfg) * 64 + lane;
    const half8* pl = WpkLo + (((size_t)which * 8 + s) * 16 + nfg) * 64 + lane;
    #pragma unroll
    for (int f = 0; f < 4; ++f) {
      half8 BH = ph[f * 64];
      half8 BL = pl[f * 64];
      acc[f] = mfma16(ahi[s], BH, acc[f]);
      acc[f] = mfma16(ahi[s], BL, acc[f]);
      acc[f] = mfma16(alo[s], BH, acc[f]);
    }
  }

  // bias + relu (+ V last-key zero) -> LDS tile [t'][j]
  #pragma unroll
  for (int f = 0; f < 4; ++f) {
    float bj = bias[blockIdx.x * 64 + f * 16 + l15];
    #pragma unroll
    for (int r = 0; r < 4; ++r) {
      int row = w * 16 + quad * 4 + r;      // t' within tile
      float val = fmaxf(acc[f][r] + bj, 0.0f);
      if (which == 2 && ((mbase + row) & (TSEQ - 1)) == TSEQ - 1) val = 0.0f;
      T[row * 68 + f * 16 + l15] = val;
    }
  }
  __syncthreads();

  // fragment generation (2 heads per block: hs = 0,1 -> h = blockIdx.x*2+hs)
  if (which < 2) {
    const int fq = tid >> 6, lp = tid & 63;
    const int kdc = lp >> 4, krlo = lp & 15;
    const int row = fq * 16 + krlo;
    const float sc = (which == 0) ? QK2_SCALE : 1.0f;
    #pragma unroll
    for (int hs = 0; hs < 2; ++hs) {
      const float* p = &T[row * 68 + hs * 32 + kdc * 8];
      float4 a0 = *(const float4*)p;
      float4 a1 = *(const float4*)(p + 4);
      float xs[8] = {a0.x, a0.y, a0.z, a0.w, a1.x, a1.y, a1.z, a1.w};
      half8 hi, lo;
      #pragma unroll
      for (int i = 0; i < 8; ++i) {
        float x = xs[i] * sc;
        _Float16 h = (_Float16)x;
        hi[i] = h;
        lo[i] = (_Float16)(x - (float)h);
      }
      int hn = (blockIdx.x * 2 + hs) * NB + nn;
      size_t di = ((size_t)hn * 32 + tile) * 256 + tid;
      if (which == 0) { Gqhi[di] = hi; Gqlo[di] = lo; }
      else            { Gkhi[di] = hi; Gklo[di] = lo; }
    }
    // AmaskF: mask-row A-fragment, row0 = kmask as f16 (one block per tile)
    if (which == 1 && blockIdx.x == 0 && tid < 128) {
      int c = tid >> 6, lane2 = tid & 63;
      int quad2 = lane2 >> 4, l15b = lane2 & 15;
      half8 am;
      #pragma unroll
      for (int j = 0; j < 8; ++j)
        am[j] = (l15b == 0) ? (_Float16)kmask[(size_t)nn * TSEQ + tile * 64 + c * 32 + quad2 * 8 + j]
                            : (_Float16)0.0f;
      AmaskF[(((size_t)nn * 32 + tile) * 2 + c) * 64 + lane2] = am;
    }
  } else {
    const int top = tid >> 6, mid = (tid >> 4) & 3, low = tid & 15;
    const int c = top >> 1, hh = top & 1;
    const int trow0 = (c * 4 + mid) * 8;
    float km[8];
    #pragma unroll
    for (int j = 0; j < 8; ++j)
      km[j] = kmask[(size_t)nn * TSEQ + tile * 64 + trow0 + j];
    #pragma unroll
    for (int hs = 0; hs < 2; ++hs) {
      const int col = hs * 32 + hh * 16 + low;
      half8 v8;
      #pragma unroll
      for (int j = 0; j < 8; ++j)
        v8[j] = (_Float16)(T[(trow0 + j) * 68 + col] * km[j]);
      int hn = (blockIdx.x * 2 + hs) * NB + nn;
      Gv[((size_t)hn * 32 + tile) * 256 + tid] = v8;
    }
  }
}

// ---------------- MFMA flash attention, transposed-S, key-split x2 ----------------
// S^T = K·Q^T (rows=keys, cols=q). K-hi/lo, V, and mask-frags are staged ONCE
// per block into double-buffered LDS; staging loads issue early (T14),
// ds_write after PV. SPLIT=2: 1024 blocks = one full 4-blocks/CU generation.
// No device-scope fences (R2 lesson: per-block agent fences = L2 writeback
// storms; the kernel-launch boundary orders partials for free).
__global__ __launch_bounds__(256, 4) void attn_kernel(
    const half8* __restrict__ Gqhi, const half8* __restrict__ Gqlo,
    const half8* __restrict__ Gkhi, const half8* __restrict__ Gklo,
    const half8* __restrict__ Gv, const half8* __restrict__ AmaskF,
    _Float16* __restrict__ Opf, float* __restrict__ Mp, float* __restrict__ Lp) {
  __shared__ __align__(16) half8 KhB[2][256];           // 8 KB
  __shared__ __align__(16) half8 KlB[2][256];           // 8 KB
  __shared__ __align__(16) half8 VB[2][256];            // 8 KB
  __shared__ __align__(16) half8 AB[2][128];            // 4 KB
  __shared__ __align__(16) _Float16 Pbuf[4][16][72];    // [wave][q][key], stride 144B

  const int tid = threadIdx.x;
  const int w = tid >> 6, lane = tid & 63;
  const int l15 = lane & 15, quad = lane >> 4;

  const int b = blockIdx.x;
  const int g    = ((b & 7) << 1) | ((b >> 3) & 1);   // hn, XCD-pinned
  const int qt   = (b >> 4) & 31;
  const int sblk = b >> 9;                            // 0..1
  const int n = g & 1;

  const size_t fbase = (size_t)g * 32 * 256;
  const int tile0 = sblk * TILES_PER;

  // Q fragment (B-operand): col q = w*16 + l15, k(d) = quad*8..+8
  half8 qhi = Gqhi[fbase + (size_t)qt * 256 + w * 64 + lane];
  half8 qlo = Gqlo[fbase + (size_t)qt * 256 + w * 64 + lane];

  float m_q = -1.0e30f;
  f32x4 O0, O1, Ol;
  O0 = (f32x4){0.f, 0.f, 0.f, 0.f};
  O1 = (f32x4){0.f, 0.f, 0.f, 0.f};
  Ol = (f32x4){0.f, 0.f, 0.f, 0.f};

  const half8* gkh = Gkhi + fbase + (size_t)tile0 * 256;
  const half8* gkl = Gklo + fbase + (size_t)tile0 * 256;
  const half8* gvv = Gv   + fbase + (size_t)tile0 * 256;
  const half8* gam = AmaskF + (size_t)(n * 32 + tile0) * 128;

  // stage tile 0
  KhB[0][tid] = gkh[tid];
  KlB[0][tid] = gkl[tid];
  VB[0][tid]  = gvv[tid];
  if (tid < 128) AB[0][tid] = gam[tid];
  __syncthreads();

  #pragma unroll
  for (int tt = 0; tt < TILES_PER; ++tt) {
    const int cur = tt & 1, nxt = cur ^ 1;
    // issue next-tile loads early; ds_write after PV (latency hides under MFMA)
    half8 rkh, rkl, rv, ra;
    if (tt < TILES_PER - 1) {
      rkh = gkh[(tt + 1) * 256 + tid];
      rkl = gkl[(tt + 1) * 256 + tid];
      rv  = gvv[(tt + 1) * 256 + tid];
      if (tid < 128) ra = gam[(tt + 1) * 128 + tid];
    }

    // S^T = K Q^T (split-fp16): rows = keys f*16+quad*4+r, col = q = l15
    f32x4 S[4];
    #pragma unroll
    for (int f = 0; f < 4; ++f) {
      half8 KH = KhB[cur][f * 64 + lane];
      half8 KL = KlB[cur][f * 64 + lane];
      f32x4 a = (f32x4){0.f, 0.f, 0.f, 0.f};
      a = mfma16(KL, qhi, a);
      a = mfma16(KH, qlo, a);
      a = mfma16(KH, qhi, a);
      S[f] = a;
    }

    // per-q max: balanced tree + 2 shuffle stages
    float t0 = fmaxf(fmaxf(S[0][0], S[0][1]), fmaxf(S[0][2], S[0][3]));
    float t1 = fmaxf(fmaxf(S[1][0], S[1][1]), fmaxf(S[1][2], S[1][3]));
    float t2 = fmaxf(fmaxf(S[2][0], S[2][1]), fmaxf(S[2][2], S[2][3]));
    float t3 = fmaxf(fmaxf(S[3][0], S[3][1]), fmaxf(S[3][2], S[3][3]));
    float mx = fmaxf(fmaxf(t0, t1), fmaxf(t2, t3));
    mx = fmaxf(mx, __shfl_xor(mx, 16));
    mx = fmaxf(mx, __shfl_xor(mx, 32));

    float mnew = fmaxf(m_q, mx);
    float alpha = exp2fast(m_q - mnew);
    m_q = mnew;

    // P = exp2(S - m), pack pairs along keys -> Pbuf[q][key] (8B stores)
    #pragma unroll
    for (int f = 0; f < 4; ++f) {
      float p0 = exp2fast(S[f][0] - m_q);
      float p1 = exp2fast(S[f][1] - m_q);
      float p2 = exp2fast(S[f][2] - m_q);
      float p3 = exp2fast(S[f][3] - m_q);
      half2t a01 = pkrtz(p0, p1);
      half2t a23 = pkrtz(p2, p3);
      half4t pk4;
      pk4[0] = a01[0]; pk4[1] = a01[1]; pk4[2] = a23[0]; pk4[3] = a23[1];
      *(half4t*)&Pbuf[w][l15][f * 16 + quad * 4] = pk4;
    }
    #pragma unroll
    for (int r = 0; r < 4; ++r) { O0[r] *= alpha; O1[r] *= alpha; }
    Ol[0] *= alpha;
    // in-wave LDS RAW: drain DS queue before reading P as B-fragments
    asm volatile("s_waitcnt lgkmcnt(0)" ::: "memory");

    half8 am0 = AB[cur][lane];
    half8 am1 = AB[cur][64 + lane];
    const half8* vbuf = (const half8*)VB[cur];
    #pragma unroll
    for (int c = 0; c < 2; ++c) {
      half8 pb = *(const half8*)&Pbuf[w][l15][c * 32 + quad * 8];
      O0 = mfma16(vbuf[(c * 2 + 0) * 64 + lane], pb, O0);
      O1 = mfma16(vbuf[(c * 2 + 1) * 64 + lane], pb, O1);
      Ol = mfma16(c == 0 ? am0 : am1, pb, Ol);
    }

    if (tt < TILES_PER - 1) {
      KhB[nxt][tid] = rkh;
      KlB[nxt][tid] = rkl;
      VB[nxt][tid]  = rv;
      if (tid < 128) AB[nxt][tid] = ra;
    }
    __syncthreads();
  }

  // epilogue: f16 partials (d = quad*4..+4 and +16), m/l from quad 0
  {
    int q = qt * 64 + w * 16 + l15;
    size_t idx = ((size_t)(sblk * 16 + g) * TSEQ + q) * DHEAD;
    half4t o0 = {(_Float16)O0[0], (_Float16)O0[1], (_Float16)O0[2], (_Float16)O0[3]};
    half4t o1 = {(_Float16)O1[0], (_Float16)O1[1], (_Float16)O1[2], (_Float16)O1[3]};
    *(half4t*)&Opf[idx + quad * 4]      = o0;
    *(half4t*)&Opf[idx + 16 + quad * 4] = o1;
    if (quad == 0) {
      Mp[(size_t)(sblk * 16 + g) * TSEQ + q] = m_q;
      Lp[(size_t)(sblk * 16 + g) * TSEQ + q] = Ol[0];
    }
  }
}

// ---------------- fused 2-way combine + layernorm + weight ----------------
__global__ __launch_bounds__(256) void ln_kernel(
    const _Float16* __restrict__ Opf, const float* __restrict__ Mp, const float* __restrict__ Lp,
    const float* __restrict__ gamma, const float* __restrict__ beta,
    const float* __restrict__ qmask,
    float* __restrict__ out, float* __restrict__ wout) {
  const int wid = threadIdx.x >> 6, lane = threadIdx.x & 63;
  const int row = blockIdx.x * 4 + wid;
  const int n = row >> 11, q = row & (TSEQ - 1);
  const int hh = lane >> 3;
  const int hn = hh * NB + n;
  const int dbase = (lane & 7) * 4;

  float m[SPLIT], l[SPLIT];
  half4t P[SPLIT];
  #pragma unroll
  for (int i = 0; i < SPLIT; ++i) {
    size_t si = (size_t)(i * 16 + hn) * TSEQ + q;
    P[i] = *(const half4t*)&Opf[si * DHEAD + dbase];
    m[i] = Mp[si];
    l[i] = Lp[si];
  }
  float mm = m[0];
  #pragma unroll
  for (int i = 1; i < SPLIT; ++i) mm = fmaxf(mm, m[i]);
  float denom = 0.f;
  float a[SPLIT];
  #pragma unroll
  for (int i = 0; i < SPLIT; ++i) { a[i] = exp2fast(m[i] - mm); denom += l[i] * a[i]; }
  float qm = qmask[row];
  float inv = qm / denom;

  float4 x = make_float4(0.f, 0.f, 0.f, 0.f);
  #pragma unroll
  for (int i = 0; i < SPLIT; ++i) {
    x.x += (float)P[i][0] * a[i]; x.y += (float)P[i][1] * a[i];
    x.z += (float)P[i][2] * a[i]; x.w += (float)P[i][3] * a[i];
  }
  x.x *= inv; x.y *= inv; x.z *= inv; x.w *= inv;

  float s = x.x + x.y + x.z + x.w;
  #pragma unroll
  for (int off = 32; off > 0; off >>= 1) s += __shfl_xor(s, off);
  float mu = s * (1.0f / H_DIM);
  float dx0 = x.x - mu, dx1 = x.y - mu, dx2 = x.z - mu, dx3 = x.w - mu;
  float sq = dx0 * dx0 + dx1 * dx1 + dx2 * dx2 + dx3 * dx3;
  #pragma unroll
  for (int off = 32; off > 0; off >>= 1) sq += __shfl_xor(sq, off);
  float rstd = rsqrtf(sq * (1.0f / H_DIM) + LN_EPS);
  float4 g = *(const float4*)(gamma + lane * 4);
  float4 bb = *(const float4*)(beta + lane * 4);
  float4 y;
  y.x = dx0 * rstd * g.x + bb.x;
  y.y = dx1 * rstd * g.y + bb.y;
  y.z = dx2 * rstd * g.z + bb.z;
  y.w = dx3 * rstd * g.w + bb.w;
  *(float4*)(out + (size_t)row * H_DIM + lane * 4) = y;
  if (lane == 0) wout[row] = qm * (1.0f / TSEQ);
}

extern "C" void kernel_launch(void* const* d_in, const int* in_sizes, int n_in,
                              void* d_out, int out_size, void* d_ws, size_t ws_size,
                              hipStream_t stream) {
  const float* Q  = (const float*)d_in[0];
  const float* K  = (const float*)d_in[1];
  const float* V  = (const float*)d_in[2];
  const float* Wq = (const float*)d_in[3];
  const float* bq = (const float*)d_in[4];
  const float* Wk = (const float*)d_in[5];
  const float* bk = (const float*)d_in[6];
  const float* Wv = (const float*)d_in[7];
  const float* bv = (const float*)d_in[8];
  const float* gamma = (const float*)d_in[9];
  const float* beta  = (const float*)d_in[10];

  char* ws = (char*)d_ws;
  const size_t NFRAG = (size_t)16 * 32 * 256;            // frags per array
  _Float16* Opf = (_Float16*)ws;                          // [SPLIT][16][TSEQ][32] f16
  half8* Gqhi = (half8*)(ws + (size_t)SPLIT * 16 * TSEQ * DHEAD * 2);
  half8* Gqlo = Gqhi + NFRAG;
  half8* Gkhi = Gqlo + NFRAG;
  half8* Gklo = Gkhi + NFRAG;
  half8* Gv   = Gklo + NFRAG;
  float* Mp = (float*)(Gv + NFRAG);                       // [SPLIT][16][TSEQ]
  float* Lp = Mp + SPLIT * 16 * TSEQ;
  float* qmask = Lp + SPLIT * 16 * TSEQ;
  float* kmask = qmask + NB * TSEQ;
  half8* WpkHi = (half8*)(kmask + NB * TSEQ);
  half8* WpkLo = WpkHi + 24576;
  half8* AmaskF = WpkLo + 24576;                          // [NB][32][2][64]

  float* out  = (float*)d_out;
  float* wout = out + (size_t)NB * TSEQ * H_DIM;

  hipLaunchKernelGGL(pack_mask_kernel, dim3(1024 + 96), dim3(256), 0, stream,
                     K, Wq, Wk, Wv, kmask, WpkHi, WpkLo);
  hipLaunchKernelGGL(proj_kernel, dim3(H_DIM / 64, NB * TSEQ / 64, 3), dim3(256), 0, stream,
                     Q, K, V, bq, bk, bv, WpkHi, WpkLo, kmask,
                     Gqhi, Gqlo, Gkhi, Gklo, Gv, AmaskF, qmask);
  hipLaunchKernelGGL(attn_kernel, dim3(16 * 32 * SPLIT), dim3(256), 0, stream,
                     Gqhi, Gqlo, Gkhi, Gklo, Gv, AmaskF, Opf, Mp, Lp);
  hipLaunchKernelGGL(ln_kernel, dim3(NB * TSEQ / 4), dim3(256), 0, stream,
                     Opf, Mp, Lp, gamma, beta, qmask, out, wout);
}

// Round 6
// 124.370 us; speedup vs baseline: 1.4853x; 1.0233x over previous
//
#include <hip/hip_runtime.h>
#include <math.h>

// Problem constants (fixed by reference)
#define H_DIM 256
#define NHEAD 8
#define DHEAD 32
#define NB 2
#define TSEQ 2048
#define LN_EPS 1e-5f

// softmax in exp2 domain: logit2 = s * (100/sqrt(32)) * log2(e).
// QK2_SCALE is folded into the packed Q fragments (proj frag-gen).
#define QK2_SCALE 25.503486f
#define SPLIT 4                         // key-split factor
#define TILES_PER (TSEQ / 64 / SPLIT)   // 8 k-tiles per block

typedef _Float16 half8 __attribute__((ext_vector_type(8)));
typedef _Float16 half4t __attribute__((ext_vector_type(4)));
typedef _Float16 half2t __attribute__((ext_vector_type(2)));
typedef float f32x4 __attribute__((ext_vector_type(4)));

__device__ __forceinline__ f32x4 mfma16(half8 a, half8 b, f32x4 c) {
  return __builtin_amdgcn_mfma_f32_16x16x32_f16(a, b, c, 0, 0, 0);
}
__device__ __forceinline__ float exp2fast(float x) {
  return __builtin_amdgcn_exp2f(x);
}
__device__ __forceinline__ half2t pkrtz(float a, float b) {
  return __builtin_bit_cast(half2t, __builtin_amdgcn_cvt_pkrtz(a, b));
}

// direct global->LDS DMA, 16B per lane (dest must be linear in tid: ours is)
#define GLOAD_LDS(gp, lp)                                            \
  __builtin_amdgcn_global_load_lds(                                  \
      (const __attribute__((address_space(1))) void*)(gp),           \
      (__attribute__((address_space(3))) void*)(lp), 16, 0, 0)

// ---------------- kmask + W pre-pack ----------------
// blocks < 1024: kmask = sign(sum|x|) per row of K (4 rows/block).
// blocks >= 1024: W fp32 -> hi/lo f16 B-fragment layout.
// qmask lives in proj_kernel (Q rows are already loaded there in fp32).
__global__ __launch_bounds__(256) void pack_mask_kernel(
    const float* __restrict__ K,
    const float* __restrict__ Wq, const float* __restrict__ Wk, const float* __restrict__ Wv,
    float* __restrict__ kmask,
    half8* __restrict__ WpkHi, half8* __restrict__ WpkLo) {
  const int tid = threadIdx.x;
  if (blockIdx.x < 1024) {
    const int wid = tid >> 6, lane = tid & 63;
    int row = blockIdx.x * 4 + wid;                 // 0..4095 (NB*TSEQ K rows)
    const float* src = K + (size_t)row * H_DIM;
    float4 v = *(const float4*)(src + lane * 4);
    float s = fabsf(v.x) + fabsf(v.y) + fabsf(v.z) + fabsf(v.w);
    #pragma unroll
    for (int off = 32; off > 0; off >>= 1) s += __shfl_xor(s, off);
    if (lane == 0) kmask[row] = (s != 0.0f) ? 1.0f : 0.0f;
    return;
  }
  int slot = (blockIdx.x - 1024) * 256 + tid;   // 0..24575
  int lane = slot & 63;
  int fg = (slot >> 6) & 15;
  int s  = (slot >> 10) & 7;
  int which = slot >> 13;
  const float* W = which == 0 ? Wq : which == 1 ? Wk : Wv;
  int j  = fg * 16 + (lane & 15);
  int kb = s * 32 + (lane >> 4) * 8;
  half8 hi, lo;
  #pragma unroll
  for (int jj = 0; jj < 8; ++jj) {
    float x = W[(size_t)(kb + jj) * H_DIM + j];
    _Float16 h = (_Float16)x;
    hi[jj] = h;
    lo[jj] = (_Float16)(x - (float)h);
  }
  WpkHi[slot] = hi;
  WpkLo[slot] = lo;
}

// ---------------- fused projection + frag repack (+ AmaskF/qmask emit) ---------
// relu(X@W+b) via split-fp16 MFMA; result tile (64 t x 64 j = 2 heads) goes
// through LDS transpose and exits directly as MFMA fragment arrays.
// __launch_bounds__(256,3): grid is 768 = exactly 3 blocks/CU; cap VGPR so the
// whole kernel runs as a single resident generation.
__global__ __launch_bounds__(256, 3) void proj_kernel(
    const float* __restrict__ Q, const float* __restrict__ K, const float* __restrict__ V,
    const float* __restrict__ bq, const float* __restrict__ bk, const float* __restrict__ bv,
    const half8* __restrict__ WpkHi, const half8* __restrict__ WpkLo,
    const float* __restrict__ kmask,
    half8* __restrict__ Gqhi, half8* __restrict__ Gqlo,
    half8* __restrict__ Gkhi, half8* __restrict__ Gklo, half8* __restrict__ Gv,
    half8* __restrict__ AmaskF, float* __restrict__ qmask) {
  const int which = blockIdx.z;
  const float* X    = which == 0 ? Q  : which == 1 ? K  : V;
  const float* bias = which == 0 ? bq : which == 1 ? bk : bv;

  __shared__ __align__(16) float T[64 * 68];   // 17408 B, stride 68 words

  const int tid = threadIdx.x;
  const int w = tid >> 6, lane = tid & 63;
  const int l15 = lane & 15, quad = lane >> 4;
  const int mbase = blockIdx.y * 64;
  const int nfg   = blockIdx.x * 4;
  const int nn   = mbase >> 11;        // batch
  const int tile = blockIdx.y & 31;    // 64-row tile within batch

  half8 ahi[8], alo[8];
  {
    const bool doqm = (which == 0) && (blockIdx.x == 0);
    float sabs = 0.0f;
    const float* xrow = X + (size_t)(mbase + w * 16 + l15) * H_DIM + quad * 8;
    #pragma unroll
    for (int s = 0; s < 8; ++s) {
      float4 a0 = *(const float4*)(xrow + s * 32);
      float4 a1 = *(const float4*)(xrow + s * 32 + 4);
      float xs[8] = {a0.x, a0.y, a0.z, a0.w, a1.x, a1.y, a1.z, a1.w};
      if (doqm) {
        #pragma unroll
        for (int i = 0; i < 8; ++i) sabs += fabsf(xs[i]);
      }
      #pragma unroll
      for (int i = 0; i < 8; ++i) {
        _Float16 h = (_Float16)xs[i];
        ahi[s][i] = h;
        alo[s][i] = (_Float16)(xs[i] - (float)h);
      }
    }
    if (doqm) {
      sabs += __shfl_xor(sabs, 16);
      sabs += __shfl_xor(sabs, 32);
      if (quad == 0) qmask[mbase + w * 16 + l15] = (sabs != 0.0f) ? 1.0f : 0.0f;
    }
  }

  f32x4 acc[4];
  #pragma unroll
  for (int f = 0; f < 4; ++f) acc[f] = (f32x4){0.f, 0.f, 0.f, 0.f};

  #pragma unroll
  for (int s = 0; s < 8; ++s) {
    const half8* ph = WpkHi + (((size_t)which * 8 + s) * 16 + nfg) * 64 + lane;
    const half8* pl = WpkLo + (((size_t)which * 8 + s) * 16 + nfg) * 64 + lane;
    #pragma unroll
    for (int f = 0; f < 4; ++f) {
      half8 BH = ph[f * 64];
      half8 BL = pl[f * 64];
      acc[f] = mfma16(ahi[s], BH, acc[f]);
      acc[f] = mfma16(ahi[s], BL, acc[f]);
      acc[f] = mfma16(alo[s], BH, acc[f]);
    }
  }

  // bias + relu (+ V last-key zero) -> LDS tile [t'][j]
  #pragma unroll
  for (int f = 0; f < 4; ++f) {
    float bj = bias[blockIdx.x * 64 + f * 16 + l15];
    #pragma unroll
    for (int r = 0; r < 4; ++r) {
      int row = w * 16 + quad * 4 + r;      // t' within tile
      float val = fmaxf(acc[f][r] + bj, 0.0f);
      if (which == 2 && ((mbase + row) & (TSEQ - 1)) == TSEQ - 1) val = 0.0f;
      T[row * 68 + f * 16 + l15] = val;
    }
  }
  __syncthreads();

  // fragment generation (2 heads per block: hs = 0,1 -> h = blockIdx.x*2+hs)
  if (which < 2) {
    const int fq = tid >> 6, lp = tid & 63;
    const int kdc = lp >> 4, krlo = lp & 15;
    const int row = fq * 16 + krlo;
    const float sc = (which == 0) ? QK2_SCALE : 1.0f;
    #pragma unroll
    for (int hs = 0; hs < 2; ++hs) {
      const float* p = &T[row * 68 + hs * 32 + kdc * 8];
      float4 a0 = *(const float4*)p;
      float4 a1 = *(const float4*)(p + 4);
      float xs[8] = {a0.x, a0.y, a0.z, a0.w, a1.x, a1.y, a1.z, a1.w};
      half8 hi, lo;
      #pragma unroll
      for (int i = 0; i < 8; ++i) {
        float x = xs[i] * sc;
        _Float16 h = (_Float16)x;
        hi[i] = h;
        lo[i] = (_Float16)(x - (float)h);
      }
      int hn = (blockIdx.x * 2 + hs) * NB + nn;
      size_t di = ((size_t)hn * 32 + tile) * 256 + tid;
      if (which == 0) { Gqhi[di] = hi; Gqlo[di] = lo; }
      else            { Gkhi[di] = hi; Gklo[di] = lo; }
    }
    // AmaskF: mask-row A-fragment, row0 = kmask as f16 (one block per tile)
    if (which == 1 && blockIdx.x == 0 && tid < 128) {
      int c = tid >> 6, lane2 = tid & 63;
      int quad2 = lane2 >> 4, l15b = lane2 & 15;
      half8 am;
      #pragma unroll
      for (int j = 0; j < 8; ++j)
        am[j] = (l15b == 0) ? (_Float16)kmask[(size_t)nn * TSEQ + tile * 64 + c * 32 + quad2 * 8 + j]
                            : (_Float16)0.0f;
      AmaskF[(((size_t)nn * 32 + tile) * 2 + c) * 64 + lane2] = am;
    }
  } else {
    const int top = tid >> 6, mid = (tid >> 4) & 3, low = tid & 15;
    const int c = top >> 1, hh = top & 1;
    const int trow0 = (c * 4 + mid) * 8;
    float km[8];
    #pragma unroll
    for (int j = 0; j < 8; ++j)
      km[j] = kmask[(size_t)nn * TSEQ + tile * 64 + trow0 + j];
    #pragma unroll
    for (int hs = 0; hs < 2; ++hs) {
      const int col = hs * 32 + hh * 16 + low;
      half8 v8;
      #pragma unroll
      for (int j = 0; j < 8; ++j)
        v8[j] = (_Float16)(T[(trow0 + j) * 68 + col] * km[j]);
      int hn = (blockIdx.x * 2 + hs) * NB + nn;
      Gv[((size_t)hn * 32 + tile) * 256 + tid] = v8;
    }
  }
}

// ---------------- MFMA flash attention, 128q x 512keys per block ----------------
// S^T = K·Q^T (rows=keys, cols=q). Each wave owns TWO independent 16-col
// q-fragments (A/B): per staged 64-key tile it runs QK(A)+QK(B) off one K read,
// then two independent softmax+PV chains — phase B's VALU fills phase A's
// lgkmcnt/exp2 latency, barriers per unit work are halved, K/V staging traffic
// per MFMA is halved. Staging is global_load_lds (dest linear in tid) —
// no staging VGPRs, writes land in LDS before the tile barrier (syncthreads
// drains vmcnt). Pbuf is reused A->B (same-wave DS ordering makes WAR safe).
// 1024 blocks = 4 blocks/CU (LDS 37.5 KB), grid: 16 hn x 16 qt x 4 sblk.
__global__ __launch_bounds__(256, 4) void attn_kernel(
    const half8* __restrict__ Gqhi, const half8* __restrict__ Gqlo,
    const half8* __restrict__ Gkhi, const half8* __restrict__ Gklo,
    const half8* __restrict__ Gv, const half8* __restrict__ AmaskF,
    _Float16* __restrict__ Opf, float* __restrict__ Mp, float* __restrict__ Lp) {
  __shared__ __align__(16) half8 KhB[2][256];           // 8 KB
  __shared__ __align__(16) half8 KlB[2][256];           // 8 KB
  __shared__ __align__(16) half8 VB[2][256];            // 8 KB
  __shared__ __align__(16) half8 AB[2][128];            // 4 KB
  __shared__ __align__(16) _Float16 Pbuf[4][16][72];    // [wave][q][key], stride 144B

  const int tid = threadIdx.x;
  const int w = tid >> 6, lane = tid & 63;
  const int l15 = lane & 15, quad = lane >> 4;

  const int b = blockIdx.x;
  const int g    = ((b & 7) << 1) | ((b >> 3) & 1);   // hn 0..15, XCD-pinned
  const int qt   = (b >> 4) & 15;                     // 128-q tile
  const int sblk = b >> 8;                            // 0..3
  const int n = g & 1;

  const size_t fbase = (size_t)g * 32 * 256;
  const int tile0 = sblk * TILES_PER;

  // two Q fragments (B-operand): 64-col tiles qt*2 and qt*2+1
  const size_t qoff = fbase + (size_t)(qt * 2) * 256 + w * 64 + lane;
  half8 qhiA = Gqhi[qoff];
  half8 qloA = Gqlo[qoff];
  half8 qhiB = Gqhi[qoff + 256];
  half8 qloB = Gqlo[qoff + 256];

  float mA = -1.0e30f, mB = -1.0e30f;
  f32x4 O0A = {0.f,0.f,0.f,0.f}, O1A = O0A, OlA = O0A;
  f32x4 O0B = O0A, O1B = O0A, OlB = O0A;

  const half8* gkh = Gkhi + fbase + (size_t)tile0 * 256;
  const half8* gkl = Gklo + fbase + (size_t)tile0 * 256;
  const half8* gvv = Gv   + fbase + (size_t)tile0 * 256;
  const half8* gam = AmaskF + (size_t)(n * 32 + tile0) * 128;

  // stage tile 0 (direct-to-LDS DMA; syncthreads drains vmcnt)
  GLOAD_LDS(gkh + tid, &KhB[0][tid]);
  GLOAD_LDS(gkl + tid, &KlB[0][tid]);
  GLOAD_LDS(gvv + tid, &VB[0][tid]);
  if (tid < 128) GLOAD_LDS(gam + tid, &AB[0][tid]);
  __syncthreads();

  #pragma unroll
  for (int tt = 0; tt < TILES_PER; ++tt) {
    const int cur = tt & 1, nxt = cur ^ 1;
    // issue next-tile DMA early; lands in LDS under this tile's compute
    if (tt < TILES_PER - 1) {
      GLOAD_LDS(gkh + (tt + 1) * 256 + tid, &KhB[nxt][tid]);
      GLOAD_LDS(gkl + (tt + 1) * 256 + tid, &KlB[nxt][tid]);
      GLOAD_LDS(gvv + (tt + 1) * 256 + tid, &VB[nxt][tid]);
      if (tid < 128) GLOAD_LDS(gam + (tt + 1) * 128 + tid, &AB[nxt][tid]);
    }

    // S^T = K Q^T for both q-fragments off one K read
    f32x4 SA[4], SB[4];
    #pragma unroll
    for (int f = 0; f < 4; ++f) {
      half8 KH = KhB[cur][f * 64 + lane];
      half8 KL = KlB[cur][f * 64 + lane];
      f32x4 a = (f32x4){0.f, 0.f, 0.f, 0.f};
      a = mfma16(KL, qhiA, a);
      a = mfma16(KH, qloA, a);
      a = mfma16(KH, qhiA, a);
      SA[f] = a;
      f32x4 bb = (f32x4){0.f, 0.f, 0.f, 0.f};
      bb = mfma16(KL, qhiB, bb);
      bb = mfma16(KH, qloB, bb);
      bb = mfma16(KH, qhiB, bb);
      SB[f] = bb;
    }

    half8 am0 = AB[cur][lane];
    half8 am1 = AB[cur][64 + lane];
    const half8* vbuf = (const half8*)VB[cur];

    // ---- phase macro: softmax + PV for one q-fragment ----
#define SM_PV(S, m_q, O0, O1, Ol)                                              \
    {                                                                          \
      float t0 = fmaxf(fmaxf(S[0][0], S[0][1]), fmaxf(S[0][2], S[0][3]));      \
      float t1 = fmaxf(fmaxf(S[1][0], S[1][1]), fmaxf(S[1][2], S[1][3]));      \
      float t2 = fmaxf(fmaxf(S[2][0], S[2][1]), fmaxf(S[2][2], S[2][3]));      \
      float t3 = fmaxf(fmaxf(S[3][0], S[3][1]), fmaxf(S[3][2], S[3][3]));      \
      float mx = fmaxf(fmaxf(t0, t1), fmaxf(t2, t3));                          \
      mx = fmaxf(mx, __shfl_xor(mx, 16));                                      \
      mx = fmaxf(mx, __shfl_xor(mx, 32));                                      \
      float mnew = fmaxf(m_q, mx);                                             \
      float alpha = exp2fast(m_q - mnew);                                      \
      m_q = mnew;                                                              \
      _Pragma("unroll")                                                        \
      for (int f = 0; f < 4; ++f) {                                            \
        float p0 = exp2fast(S[f][0] - m_q);                                    \
        float p1 = exp2fast(S[f][1] - m_q);                                    \
        float p2 = exp2fast(S[f][2] - m_q);                                    \
        float p3 = exp2fast(S[f][3] - m_q);                                    \
        half2t a01 = pkrtz(p0, p1);                                            \
        half2t a23 = pkrtz(p2, p3);                                            \
        half4t pk4;                                                            \
        pk4[0] = a01[0]; pk4[1] = a01[1]; pk4[2] = a23[0]; pk4[3] = a23[1];    \
        *(half4t*)&Pbuf[w][l15][f * 16 + quad * 4] = pk4;                      \
      }                                                                        \
      _Pragma("unroll")                                                        \
      for (int r = 0; r < 4; ++r) { O0[r] *= alpha; O1[r] *= alpha; }          \
      Ol[0] *= alpha;                                                          \
      asm volatile("s_waitcnt lgkmcnt(0)" ::: "memory");                       \
      _Pragma("unroll")                                                        \
      for (int c = 0; c < 2; ++c) {                                            \
        half8 pb = *(const half8*)&Pbuf[w][l15][c * 32 + quad * 8];            \
        O0 = mfma16(vbuf[(c * 2 + 0) * 64 + lane], pb, O0);                    \
        O1 = mfma16(vbuf[(c * 2 + 1) * 64 + lane], pb, O1);                    \
        Ol = mfma16(c == 0 ? am0 : am1, pb, Ol);                               \
      }                                                                        \
    }

    SM_PV(SA, mA, O0A, O1A, OlA)
    SM_PV(SB, mB, O0B, O1B, OlB)
#undef SM_PV

    __syncthreads();   // next-tile DMA complete (vmcnt drained) + LDS reads done
  }

  // epilogue: f16 partials for both q-fragments, m/l from quad 0
  {
    int qA = qt * 128 + w * 16 + l15;
    size_t rowbase = (size_t)(sblk * 16 + g) * TSEQ;
    size_t idxA = (rowbase + qA) * DHEAD;
    size_t idxB = (rowbase + qA + 64) * DHEAD;
    half4t o0A = {(_Float16)O0A[0], (_Float16)O0A[1], (_Float16)O0A[2], (_Float16)O0A[3]};
    half4t o1A = {(_Float16)O1A[0], (_Float16)O1A[1], (_Float16)O1A[2], (_Float16)O1A[3]};
    half4t o0B = {(_Float16)O0B[0], (_Float16)O0B[1], (_Float16)O0B[2], (_Float16)O0B[3]};
    half4t o1B = {(_Float16)O1B[0], (_Float16)O1B[1], (_Float16)O1B[2], (_Float16)O1B[3]};
    *(half4t*)&Opf[idxA + quad * 4]      = o0A;
    *(half4t*)&Opf[idxA + 16 + quad * 4] = o1A;
    *(half4t*)&Opf[idxB + quad * 4]      = o0B;
    *(half4t*)&Opf[idxB + 16 + quad * 4] = o1B;
    if (quad == 0) {
      Mp[rowbase + qA]      = mA;
      Lp[rowbase + qA]      = OlA[0];
      Mp[rowbase + qA + 64] = mB;
      Lp[rowbase + qA + 64] = OlB[0];
    }
  }
}

// ---------------- fused 4-way combine + layernorm + weight ----------------
__global__ __launch_bounds__(256) void ln_kernel(
    const _Float16* __restrict__ Opf, const float* __restrict__ Mp, const float* __restrict__ Lp,
    const float* __restrict__ gamma, const float* __restrict__ beta,
    const float* __restrict__ qmask,
    float* __restrict__ out, float* __restrict__ wout) {
  const int wid = threadIdx.x >> 6, lane = threadIdx.x & 63;
  const int row = blockIdx.x * 4 + wid;
  const int n = row >> 11, q = row & (TSEQ - 1);
  const int hh = lane >> 3;
  const int hn = hh * NB + n;
  const int dbase = (lane & 7) * 4;

  float m[SPLIT], l[SPLIT];
  half4t P[SPLIT];
  #pragma unroll
  for (int i = 0; i < SPLIT; ++i) {
    size_t si = (size_t)(i * 16 + hn) * TSEQ + q;
    P[i] = *(const half4t*)&Opf[si * DHEAD + dbase];
    m[i] = Mp[si];
    l[i] = Lp[si];
  }
  float mm = m[0];
  #pragma unroll
  for (int i = 1; i < SPLIT; ++i) mm = fmaxf(mm, m[i]);
  float denom = 0.f;
  float a[SPLIT];
  #pragma unroll
  for (int i = 0; i < SPLIT; ++i) { a[i] = exp2fast(m[i] - mm); denom += l[i] * a[i]; }
  float qm = qmask[row];
  float inv = qm / denom;

  float4 x = make_float4(0.f, 0.f, 0.f, 0.f);
  #pragma unroll
  for (int i = 0; i < SPLIT; ++i) {
    x.x += (float)P[i][0] * a[i]; x.y += (float)P[i][1] * a[i];
    x.z += (float)P[i][2] * a[i]; x.w += (float)P[i][3] * a[i];
  }
  x.x *= inv; x.y *= inv; x.z *= inv; x.w *= inv;

  float s = x.x + x.y + x.z + x.w;
  #pragma unroll
  for (int off = 32; off > 0; off >>= 1) s += __shfl_xor(s, off);
  float mu = s * (1.0f / H_DIM);
  float dx0 = x.x - mu, dx1 = x.y - mu, dx2 = x.z - mu, dx3 = x.w - mu;
  float sq = dx0 * dx0 + dx1 * dx1 + dx2 * dx2 + dx3 * dx3;
  #pragma unroll
  for (int off = 32; off > 0; off >>= 1) sq += __shfl_xor(sq, off);
  float rstd = rsqrtf(sq * (1.0f / H_DIM) + LN_EPS);
  float4 g = *(const float4*)(gamma + lane * 4);
  float4 bb = *(const float4*)(beta + lane * 4);
  float4 y;
  y.x = dx0 * rstd * g.x + bb.x;
  y.y = dx1 * rstd * g.y + bb.y;
  y.z = dx2 * rstd * g.z + bb.z;
  y.w = dx3 * rstd * g.w + bb.w;
  *(float4*)(out + (size_t)row * H_DIM + lane * 4) = y;
  if (lane == 0) wout[row] = qm * (1.0f / TSEQ);
}

extern "C" void kernel_launch(void* const* d_in, const int* in_sizes, int n_in,
                              void* d_out, int out_size, void* d_ws, size_t ws_size,
                              hipStream_t stream) {
  const float* Q  = (const float*)d_in[0];
  const float* K  = (const float*)d_in[1];
  const float* V  = (const float*)d_in[2];
  const float* Wq = (const float*)d_in[3];
  const float* bq = (const float*)d_in[4];
  const float* Wk = (const float*)d_in[5];
  const float* bk = (const float*)d_in[6];
  const float* Wv = (const float*)d_in[7];
  const float* bv = (const float*)d_in[8];
  const float* gamma = (const float*)d_in[9];
  const float* beta  = (const float*)d_in[10];

  char* ws = (char*)d_ws;
  const size_t NFRAG = (size_t)16 * 32 * 256;            // frags per array
  _Float16* Opf = (_Float16*)ws;                          // [SPLIT][16][TSEQ][32] f16
  half8* Gqhi = (half8*)(ws + (size_t)SPLIT * 16 * TSEQ * DHEAD * 2);
  half8* Gqlo = Gqhi + NFRAG;
  half8* Gkhi = Gqlo + NFRAG;
  half8* Gklo = Gkhi + NFRAG;
  half8* Gv   = Gklo + NFRAG;
  float* Mp = (float*)(Gv + NFRAG);                       // [SPLIT][16][TSEQ]
  float* Lp = Mp + SPLIT * 16 * TSEQ;
  float* qmask = Lp + SPLIT * 16 * TSEQ;
  float* kmask = qmask + NB * TSEQ;
  half8* WpkHi = (half8*)(kmask + NB * TSEQ);
  half8* WpkLo = WpkHi + 24576;
  half8* AmaskF = WpkLo + 24576;                          // [NB][32][2][64]

  float* out  = (float*)d_out;
  float* wout = out + (size_t)NB * TSEQ * H_DIM;

  hipLaunchKernelGGL(pack_mask_kernel, dim3(1024 + 96), dim3(256), 0, stream,
                     K, Wq, Wk, Wv, kmask, WpkHi, WpkLo);
  hipLaunchKernelGGL(proj_kernel, dim3(H_DIM / 64, NB * TSEQ / 64, 3), dim3(256), 0, stream,
                     Q, K, V, bq, bk, bv, WpkHi, WpkLo, kmask,
                     Gqhi, Gqlo, Gkhi, Gklo, Gv, AmaskF, qmask);
  hipLaunchKernelGGL(attn_kernel, dim3(16 * 16 * SPLIT), dim3(256), 0, stream,
                     Gqhi, Gqlo, Gkhi, Gklo, Gv, AmaskF, Opf, Mp, Lp);
  hipLaunchKernelGGL(ln_kernel, dim3(NB * TSEQ / 4), dim3(256), 0, stream,
                     Opf, Mp, Lp, gamma, beta, qmask, out, wout);
}